// Round 12
// baseline (22.800 us; speedup 1.0000x reference)
//
#include <hip/hip_runtime.h>

#define Nn 4096
#define NTRI 528              // 32*33/2 upper-tri 128x128 tiles
#define NBLK 2080             // 2*528 + 1024

typedef __attribute__((ext_vector_type(4))) float f32x4;
typedef __attribute__((ext_vector_type(2))) long  long2v;

#define C_K   0.7213475204444817f   // log2(e)/mu, mu=2
#define C_2K  1.4426950408889634f   // 2*log2(e)/mu
#define SKIP_BOUND -40.0f           // exp2(-40)*16.7M*beta ~ 1e-19 << 1e-5 threshold

// manual f32 -> fp8 e4m3fn (RNE, FTZ below 2^-6, saturate to 448)
__device__ __forceinline__ unsigned f2e4m3(float f) {
  unsigned u = __float_as_uint(f);
  unsigned s = (u >> 24) & 0x80u;
  int e = (int)((u >> 23) & 0xff);
  unsigned m = u & 0x7fffffu;
  if (e < 121) return s;                         // FTZ (|x| < 2^-6), incl. zero
  unsigned mr = m + 0x7ffffu + ((m >> 20) & 1u); // RNE to 3 mantissa bits
  if (mr & 0x800000u) { mr = 0; e += 1; }
  int code = ((e - 120) << 3) | (int)(mr >> 20);
  if (code > 0x7e) code = 0x7e;                  // clamp to 448 (no inf/nan)
  return s | (unsigned)code;
}

// ---- prep: fp8 cast into FRAGMENT-NATIVE layout + norms ----------------------
// Layout (verified absmax=0 in r11): 16-row panel p, ks-pair c in {0,1},
// MFMA lane L = kq*16 + (row&15):
//   byte offset = p*2048 + c*1024 + L*16 + (ks&1)*8 + (k&7)
// A wave's fragment load is 64 x 16B CONTIGUOUS (1KB) -> perfectly coalesced.
__global__ __launch_bounds__(256) void prep_kernel(const float* __restrict__ X,
                                                   const float* __restrict__ Y,
                                                   float* __restrict__ kn,
                                                   unsigned char* __restrict__ Xf,
                                                   unsigned char* __restrict__ Yf) {
  int wave = threadIdx.x >> 6;
  int lane = threadIdx.x & 63;
  int row = blockIdx.x * 4 + wave;            // 0..8191
  const float* src;
  unsigned char* dstm;
  int r;
  if (row < Nn) { r = row;      src = X + (size_t)r * 128; dstm = Xf; }
  else          { r = row - Nn; src = Y + (size_t)r * 128; dstm = Yf; }
  float2 v = reinterpret_cast<const float2*>(src)[lane];
  float s = v.x * v.x + v.y * v.y;
#pragma unroll
  for (int off = 32; off > 0; off >>= 1) s += __shfl_xor(s, off);
  unsigned short h = (unsigned short)(f2e4m3(v.x) | (f2e4m3(v.y) << 8));
  // this lane covers bytes k = 2*lane, 2*lane+1 of row r
  const int c    = lane >> 5;
  const int half = (lane >> 4) & 1;           // ks & 1
  const int kq   = (lane >> 2) & 3;
  const int L    = (kq << 4) + (r & 15);
  const size_t off8 = ((size_t)(r >> 4) << 11) + (c << 10) + (L << 4)
                    + (half << 3) + ((lane & 3) << 1);
  *reinterpret_cast<unsigned short*>(dstm + off8) = h;
  if (lane == 0) kn[row] = -C_K * s;
}

// ---- fused pairwise-exp-sum: LDS-FREE, barrier-free hot path ------------------
// t < 528:        q=0 (XX), upper-tri tile (by<=bx), off-diag weight 2
// 528 <= t <1056: q=1 (YY), same
// t >= 1056:      q=2 (XY), full 32x32
// Fragments load direct global->VGPR from the fragment-native buffers:
// 16 x global_load_dwordx4 per wave, each 1KB contiguous, L2-resident (1MB).
// __launch_bounds__(256,2): no spill (r10 PMC: the (256,4) 128-reg cap caused
// 145MB/dispatch scratch traffic and confounded r5/r9's LDS-free attempts).
__global__ __launch_bounds__(256, 2) void mmd_main(const unsigned char* __restrict__ Xf,
                                                   const unsigned char* __restrict__ Yf,
                                                   const float* __restrict__ kn,
                                                   float* __restrict__ partials) {
  __shared__ float red[4];

  const int t = blockIdx.x;
  int q, bx, by;
  if (t < 2 * NTRI) {
    q = (t >= NTRI) ? 1 : 0;
    const int u = t - q * NTRI;
    int r = (int)((sqrtf(8.f * (float)u + 1.f) - 1.f) * 0.5f);
    while ((r + 1) * (r + 2) / 2 <= u) ++r;
    while (r * (r + 1) / 2 > u) --r;
    bx = r; by = u - r * (r + 1) / 2;          // by <= bx
  } else {
    q = 2;
    const int u = t - 2 * NTRI;
    by = u >> 5; bx = u & 31;
  }

  const unsigned char* Asrc = (q == 1) ? Yf : Xf;
  const unsigned char* Bsrc = (q == 0) ? Xf : Yf;
  const float* knA = (q == 1) ? kn + Nn : kn;
  const float* knB = (q == 0) ? kn : kn + Nn;
  const int R0 = by << 7, C0 = bx << 7;

  const int lane = threadIdx.x & 63;
  const int wv   = threadIdx.x >> 6;
  const int wr = wv >> 1, wc = wv & 1;    // 2x2 wave grid, 64x64 per wave
  const int lr = lane & 15, kq = lane >> 4;

  // per-wave fragment bases: 4 panels of 2KB per operand
  const char* Af = (const char*)Asrc + (((size_t)((by << 3) + (wr << 2))) << 11) + (lane << 4);
  const char* Bf = (const char*)Bsrc + (((size_t)((bx << 3) + (wc << 2))) << 11) + (lane << 4);

  f32x4 acc[4][4];
#pragma unroll
  for (int m = 0; m < 4; ++m)
#pragma unroll
    for (int n = 0; n < 4; ++n)
      acc[m][n] = (f32x4){0.f, 0.f, 0.f, 0.f};

  // two K-halves (c = 0, 1): load 16KB of fragments, run 32 MFMAs; the
  // compiler hoists half-2's independent loads under half-1's MFMAs.
#pragma unroll
  for (int c = 0; c < 2; ++c) {
    long a0[4], a1[4], b0[4], b1[4];       // ks = 2c (a0/b0), 2c+1 (a1/b1)
#pragma unroll
    for (int i = 0; i < 4; ++i) {
      long2v ta = *reinterpret_cast<const long2v*>(Af + (i << 11) + (c << 10));
      a0[i] = ta[0]; a1[i] = ta[1];
      long2v tb = *reinterpret_cast<const long2v*>(Bf + (i << 11) + (c << 10));
      b0[i] = tb[0]; b1[i] = tb[1];
    }
#pragma unroll
    for (int m = 0; m < 4; ++m)
#pragma unroll
      for (int n = 0; n < 4; ++n)
        acc[m][n] = __builtin_amdgcn_mfma_f32_16x16x32_fp8_fp8(a0[m], b0[n], acc[m][n], 0, 0, 0);
#pragma unroll
    for (int m = 0; m < 4; ++m)
#pragma unroll
      for (int n = 0; n < 4; ++n)
        acc[m][n] = __builtin_amdgcn_mfma_f32_16x16x32_fp8_fp8(a1[m], b1[n], acc[m][n], 0, 0, 0);
  }

  // ---- epilogue: wave-level underflow skip, then exp2 -------------------------
  const bool diagblk = (q < 2) && (bx == by);
  f32x4 ax[4];
  float cy[4];
#pragma unroll
  for (int m = 0; m < 4; ++m)
    ax[m] = *reinterpret_cast<const f32x4*>(knA + R0 + (wr << 6) + (m << 4) + (kq << 2));
#pragma unroll
  for (int n = 0; n < 4; ++n)
    cy[n] = knB[C0 + (wc << 6) + (n << 4) + lr];

  f32x4 vm = acc[0][0];
#pragma unroll
  for (int m = 0; m < 4; ++m)
#pragma unroll
    for (int n = 0; n < 4; ++n) {
      if (m == 0 && n == 0) continue;
      vm[0] = fmaxf(vm[0], acc[m][n][0]);
      vm[1] = fmaxf(vm[1], acc[m][n][1]);
      vm[2] = fmaxf(vm[2], acc[m][n][2]);
      vm[3] = fmaxf(vm[3], acc[m][n][3]);
    }
  float amax = fmaxf(fmaxf(vm[0], vm[1]), fmaxf(vm[2], vm[3]));
  float axm = -1e30f;
#pragma unroll
  for (int m = 0; m < 4; ++m)
    axm = fmaxf(axm, fmaxf(fmaxf(ax[m][0], ax[m][1]), fmaxf(ax[m][2], ax[m][3])));
  float cym = fmaxf(fmaxf(cy[0], cy[1]), fmaxf(cy[2], cy[3]));
  float bound = fmaf(amax, C_2K, axm + cym);

  float local = 0.f;
  if (__any(bound > SKIP_BOUND)) {
    float l0 = 0.f, l1 = 0.f, l2 = 0.f, l3 = 0.f;
#pragma unroll
    for (int m = 0; m < 4; ++m) {
      const int rbase = (wr << 6) + (m << 4) + (kq << 2);
#pragma unroll
      for (int n = 0; n < 4; ++n) {
        const float e0 = __builtin_amdgcn_exp2f(fmaf(acc[m][n][0], C_2K, ax[m][0] + cy[n]));
        const float e1 = __builtin_amdgcn_exp2f(fmaf(acc[m][n][1], C_2K, ax[m][1] + cy[n]));
        const float e2 = __builtin_amdgcn_exp2f(fmaf(acc[m][n][2], C_2K, ax[m][2] + cy[n]));
        const float e3 = __builtin_amdgcn_exp2f(fmaf(acc[m][n][3], C_2K, ax[m][3] + cy[n]));
        if (diagblk) {
          const int cc = (wc << 6) + (n << 4) + lr;
          if (rbase + 0 != cc) l0 += e0;
          if (rbase + 1 != cc) l1 += e1;
          if (rbase + 2 != cc) l2 += e2;
          if (rbase + 3 != cc) l3 += e3;
        } else {
          l0 += e0; l1 += e1; l2 += e2; l3 += e3;
        }
      }
    }
    local = (l0 + l1) + (l2 + l3);
#pragma unroll
    for (int off = 32; off > 0; off >>= 1) local += __shfl_xor(local, off);
  }

  if (lane == 0) red[wv] = local;
  __syncthreads();
  if (threadIdx.x == 0) {
    float s = (red[0] + red[1]) + (red[2] + red[3]);
    float w;
    if (q < 2) w = ((bx == by) ? 1.f : 2.f) * (1.0f / 16773120.0f);  // alpha
    else       w = -2.0f / 16777216.0f;                               // -2*beta
    partials[t] = s * w;
  }
}

// ---- deterministic final reduction ------------------------------------------
__global__ __launch_bounds__(256) void mmd_final(const float* __restrict__ partials,
                                                 float* __restrict__ out) {
  float v = 0.f;
  for (int i = threadIdx.x; i < NBLK; i += 256) v += partials[i];
#pragma unroll
  for (int off = 32; off > 0; off >>= 1) v += __shfl_xor(v, off);
  __shared__ float red[4];
  if ((threadIdx.x & 63) == 0) red[threadIdx.x >> 6] = v;
  __syncthreads();
  if (threadIdx.x == 0) {
    // analytic diagonal: n*(alpha1+alpha2) = 2/4095
    out[0] = ((red[0] + red[1]) + (red[2] + red[3])) + (float)(2.0 / 4095.0);
  }
}

extern "C" void kernel_launch(void* const* d_in, const int* in_sizes, int n_in,
                              void* d_out, int out_size, void* d_ws, size_t ws_size,
                              hipStream_t stream) {
  const float* X = (const float*)d_in[0];
  const float* Y = (const float*)d_in[1];
  float* kn        = (float*)d_ws;                        // 8192 floats (-K*norm^2)
  float* partials  = kn + 8192;                           // 2080 floats
  unsigned char* Xf = (unsigned char*)(partials + 2080);  // 512 KB fragment-native fp8
  unsigned char* Yf = Xf + (size_t)Nn * 128;              // 512 KB
  float* out = (float*)d_out;

  hipLaunchKernelGGL(prep_kernel, dim3(2048), dim3(256), 0, stream, X, Y, kn, Xf, Yf);
  hipLaunchKernelGGL(mmd_main, dim3(NBLK), dim3(256), 0, stream, Xf, Yf, kn, partials);
  hipLaunchKernelGGL(mmd_final, dim3(1), dim3(256), 0, stream, partials, out);
}